// Round 8
// baseline (202.598 us; speedup 1.0000x reference)
//
#include <hip/hip_runtime.h>

#define NPIX 4096
#define NCH 72
#define NCHUNK 18
#define KPAD 96

static constexpr float SCALE_LOG2E = 0.022542110013890054f; // (1/64)*log2(e)

// ws layout (float offsets) — DC slot retained but unused (w-division fused into k_cA)
#define OFF_VC 0          // [18][4096][4] f32 chunk v; becomes v/D in-place after k_cA
#define OFF_VG 294912     // [72][4096] f32 global v (c-major)
#define OFF_DC 589824     // (unused)
#define OFF_DG 663552     // [4096] f32 (atomics; memset)
#define OFF_OUTG 667648   // [72][4096] f32 (atomics; memset, contiguous with DG)
#define OFF_OUTC 962560   // [18][4096][4] f32 (direct-stored by k_cB, pixel-major float4)
#define OFF_QB 1257472    // bf16 [4096][96] global q (scaled, zero-padded 72..95)
#define OFF_KB 1454080    // bf16 [4096][96] global k (zero-padded)
#define OFF_WB 1650688    // bf16 [80][4096] global v/D (rows 72..79 zero)
#define OFF_QCB 1814528   // bf16 [18][4096][4] chunk q (scaled), 8B/pixel
#define OFF_KCB 1961984   // bf16 [18][4096][4] chunk k, 8B/pixel
#define WS_FLOATS 2109440

typedef __attribute__((ext_vector_type(8))) short short8v;
typedef __attribute__((ext_vector_type(4))) short short4v;
typedef __attribute__((ext_vector_type(4))) float f32x4;
typedef __attribute__((ext_vector_type(16))) float f32x16;

__device__ __forceinline__ float fexp2(float x) {
#if __has_builtin(__builtin_amdgcn_exp2f)
  return __builtin_amdgcn_exp2f(x);
#else
  return exp2f(x);
#endif
}

__device__ __forceinline__ unsigned short bf16r(float f) {
  unsigned int u = __float_as_uint(f);
  u = (u + 0x7FFFu + ((u >> 16) & 1u)) >> 16;
  return (unsigned short)u;
}
__device__ __forceinline__ unsigned int bf16pair(float lo, float hi) {
  return (unsigned int)bf16r(lo) | ((unsigned int)bf16r(hi) << 16);
}

__device__ __forceinline__ f32x4 MFMA(short8v a, short8v b, f32x4 c) {
  return __builtin_amdgcn_mfma_f32_16x16x32_bf16(a, b, c, 0, 0, 0);
}
__device__ __forceinline__ f32x16 MFMA32(short8v a, short8v b, f32x16 c) {
  return __builtin_amdgcn_mfma_f32_32x32x16_bf16(a, b, c, 0, 0, 0);
}

// Build a 32x32x16 A/B fragment from 4 real bf16 (K=4): lanes hi=1 (k=8..15) and
// elems 4..7 zeroed -> K=16 acts as K=4.
__device__ __forceinline__ short8v fragz(int hi, short4v v) {
  union { int2 i2; short4v s4; } u; u.s4 = v;
  union { int4 i4; short8v s8; } r;
  r.i4.x = hi ? 0 : u.i2.x;
  r.i4.y = hi ? 0 : u.i2.y;
  r.i4.z = 0; r.i4.w = 0;
  return r.s8;
}

__device__ __forceinline__ float dot4(float4 a, float4 b) {
  return a.x*b.x + a.y*b.y + a.z*b.z + a.w*b.w;
}

__device__ __forceinline__ float4 mix4(const float* __restrict__ W, const float* __restrict__ b,
                                       float x0, float x1, float x2, float x3, float sc)
{
  float4 r;
  r.x = (b[0] + W[0]*x0  + W[1]*x1  + W[2]*x2  + W[3]*x3)  * sc;
  r.y = (b[1] + W[4]*x0  + W[5]*x1  + W[6]*x2  + W[7]*x3)  * sc;
  r.z = (b[2] + W[8]*x0  + W[9]*x1  + W[10]*x2 + W[11]*x3) * sc;
  r.w = (b[3] + W[12]*x0 + W[13]*x1 + W[14]*x2 + W[15]*x3) * sc;
  return r;
}

// grid (16, 24) x 256. seg 0..5: chunk qkv (3 chunks each). seg 6..23: global (mat m, group of 12)
__global__ __launch_bounds__(256, 3) void k_qkv(const float* __restrict__ x,
    const float* __restrict__ Wq, const float* __restrict__ bq,
    const float* __restrict__ Wk, const float* __restrict__ bk,
    const float* __restrict__ Wv, const float* __restrict__ bv,
    const float* __restrict__ WqG, const float* __restrict__ bqG,
    const float* __restrict__ WkG, const float* __restrict__ bkG,
    const float* __restrict__ WvG, const float* __restrict__ bvG,
    float* __restrict__ ws)
{
  const int p = blockIdx.x * blockDim.x + threadIdx.x;
  const int seg = blockIdx.y;
  if (seg < 6) {
    short4v* qcb = reinterpret_cast<short4v*>(ws + OFF_QCB);
    short4v* kcb = reinterpret_cast<short4v*>(ws + OFF_KCB);
    float4* vd = reinterpret_cast<float4*>(ws + OFF_VC);
    const int n0 = seg * 3;
#pragma unroll
    for (int dn = 0; dn < 3; ++dn) {
      const int n = n0 + dn;
      const float x0 = x[(4*n+0)*NPIX + p];
      const float x1 = x[(4*n+1)*NPIX + p];
      const float x2 = x[(4*n+2)*NPIX + p];
      const float x3 = x[(4*n+3)*NPIX + p];
      float4 q = mix4(Wq + n*16, bq + n*4, x0, x1, x2, x3, SCALE_LOG2E);
      float4 k = mix4(Wk + n*16, bk + n*4, x0, x1, x2, x3, 1.0f);
      float4 v = mix4(Wv + n*16, bv + n*4, x0, x1, x2, x3, 1.0f);
      short4v qs = { (short)bf16r(q.x), (short)bf16r(q.y), (short)bf16r(q.z), (short)bf16r(q.w) };
      short4v ks = { (short)bf16r(k.x), (short)bf16r(k.y), (short)bf16r(k.z), (short)bf16r(k.w) };
      qcb[(size_t)n*NPIX + p] = qs;
      kcb[(size_t)n*NPIX + p] = ks;
      vd[n*NPIX + p] = v;
    }
  } else {
    const int m = (seg - 6) / 6;
    const int g6 = (seg - 6) % 6;
    const float* W = (m == 0) ? WqG : (m == 1) ? WkG : WvG;
    const float* b = (m == 0) ? bqG : (m == 1) ? bkG : bvG;
    float4 xv[18];
#pragma unroll
    for (int c = 0; c < 18; ++c) {
      float4 t;
      t.x = x[(4*c+0)*NPIX + p];
      t.y = x[(4*c+1)*NPIX + p];
      t.z = x[(4*c+2)*NPIX + p];
      t.w = x[(4*c+3)*NPIX + p];
      xv[c] = t;
    }
    const int ob = g6 * 12;
    if (m == 2) {
      float* dst = ws + OFF_VG; // [72][4096]
      for (int o = ob; o < ob + 12; ++o) {
        float acc = b[o];
        const float4* wrow = reinterpret_cast<const float4*>(W + o*NCH);
#pragma unroll
        for (int c = 0; c < 18; ++c) acc += dot4(wrow[c], xv[c]);
        dst[o*NPIX + p] = acc;
      }
    } else {
      unsigned short* dst = reinterpret_cast<unsigned short*>(ws + ((m == 0) ? OFF_QB : OFF_KB));
      const float sc = (m == 0) ? SCALE_LOG2E : 1.0f;
      for (int o = ob; o < ob + 12; ++o) {
        float acc = b[o];
        const float4* wrow = reinterpret_cast<const float4*>(W + o*NCH);
#pragma unroll
        for (int c = 0; c < 18; ++c) acc += dot4(wrow[c], xv[c]);
        dst[p*KPAD + o] = bf16r(acc * sc);
      }
      if (g6 == 5) {
#pragma unroll
        for (int o = NCH; o < KPAD; ++o) dst[p*KPAD + o] = 0;
      }
    }
  }
}

// chunk pass A (MFMA 32x32x16): D_j = sum_i exp2(q_j.k_i), then VC[n][j] *= 1/D (fused).
// grid (32, 18) x 256.  Wave owns 32 j (MFMA cols, stationary Q); streams K rows 32/iter.
// Lane (hi,jl): j = j0+jl; 16 score regs cover i rows (r&3)+8*(r>>2)+4*hi of each tile.
__global__ __launch_bounds__(256, 2) void k_cA(float* __restrict__ ws)
{
  const int tid = threadIdx.x;
  const int w = tid >> 6, l = tid & 63;
  const int hi = l >> 5, jl = l & 31;
  const int n = blockIdx.y;
  const int j0 = blockIdx.x * 128 + w * 32;
  const short4v* qsrc = reinterpret_cast<const short4v*>(ws + OFF_QCB) + (size_t)n*NPIX;
  const short4v* ksrc = reinterpret_cast<const short4v*>(ws + OFF_KCB) + (size_t)n*NPIX;
  const short8v qb = fragz(hi, qsrc[j0 + jl]);   // stationary B-frag (col j)
  float d[16];
#pragma unroll
  for (int r = 0; r < 16; ++r) d[r] = 0.f;
  short4v kv = ksrc[jl];
  const f32x16 z16 = {0.f,0.f,0.f,0.f,0.f,0.f,0.f,0.f,0.f,0.f,0.f,0.f,0.f,0.f,0.f,0.f};
#pragma unroll 2
  for (int ib = 0; ib < NPIX; ib += 32) {
    short8v ka = fragz(hi, kv);                  // A-frag rows i = ib+jl (2-way bcast load)
    if (ib < NPIX - 32) kv = ksrc[ib + 32 + jl];
    f32x16 s = MFMA32(ka, qb, z16);
#pragma unroll
    for (int r = 0; r < 16; ++r) d[r] += fexp2(s[r]);
  }
  float dj = 0.f;
#pragma unroll
  for (int r = 0; r < 16; ++r) dj += d[r];
  dj += __shfl_xor(dj, 32, 64);                  // combine the two i-row halves
  const float inv = 1.0f / dj;                   // D[j0+jl]
  if (hi == 0) {                                 // exclusive owner of these 32 j's
    f32x4* vc = reinterpret_cast<f32x4*>(ws + OFF_VC) + (size_t)n*NPIX + j0 + jl;
    f32x4 v = *vc;
    *vc = v * inv;                               // w = v/D in place
  }
}

// global pass A (MFMA): D[j] = sum_i exp2(S[j][i]).  grid (64, 8) x 256
__global__ __launch_bounds__(256, 2) void k_mA(float* __restrict__ ws)
{
  const unsigned short* QB = reinterpret_cast<const unsigned short*>(ws + OFF_QB);
  const unsigned short* KB = reinterpret_cast<const unsigned short*>(ws + OFF_KB);
  const int w = threadIdx.x >> 6, l = threadIdx.x & 63;
  const int g = l >> 4, li = l & 15;
  const int j0 = blockIdx.x * 64 + w * 16;
  const int i0 = blockIdx.y * 512;
  short8v qa[3];
#pragma unroll
  for (int kk = 0; kk < 3; ++kk)
    qa[kk] = *reinterpret_cast<const short8v*>(QB + (j0 + li)*KPAD + kk*32 + 8*g);
  float ds0 = 0.f, ds1 = 0.f, ds2 = 0.f, ds3 = 0.f;
  for (int t = 0; t < 32; ++t) {
    const int i = i0 + t*16;
    f32x4 acc = {0.f, 0.f, 0.f, 0.f};
#pragma unroll
    for (int kk = 0; kk < 3; ++kk) {
      short8v kb = *reinterpret_cast<const short8v*>(KB + (i + li)*KPAD + kk*32 + 8*g);
      acc = MFMA(qa[kk], kb, acc);
    }
    ds0 += fexp2(acc[0]);
    ds1 += fexp2(acc[1]);
    ds2 += fexp2(acc[2]);
    ds3 += fexp2(acc[3]);
  }
#pragma unroll
  for (int m = 1; m < 16; m <<= 1) {
    ds0 += __shfl_xor(ds0, m, 64);
    ds1 += __shfl_xor(ds1, m, 64);
    ds2 += __shfl_xor(ds2, m, 64);
    ds3 += __shfl_xor(ds3, m, 64);
  }
  if (li == 0) {
    float* D = ws + OFF_DG;
    atomicAdd(&D[j0 + 4*g + 0], ds0);
    atomicAdd(&D[j0 + 4*g + 1], ds1);
    atomicAdd(&D[j0 + 4*g + 2], ds2);
    atomicAdd(&D[j0 + 4*g + 3], ds3);
  }
}

// global w only: WB = bf16(VG/D).  grid (16) x 256
__global__ void k_wcompG(float* __restrict__ ws)
{
  const int j = blockIdx.x * blockDim.x + threadIdx.x; // 0..4095
  const float inv = 1.0f / ws[OFF_DG + j];
  unsigned short* WB = reinterpret_cast<unsigned short*>(ws + OFF_WB);
  const float* VG = ws + OFF_VG;
#pragma unroll
  for (int c = 0; c < NCH; ++c)
    WB[c*NPIX + j] = bf16r(VG[c*NPIX + j] * inv);
#pragma unroll
  for (int c = NCH; c < 80; ++c) WB[c*NPIX + j] = 0;
}

// chunk pass B (MFMA 32x32x16): OUTC[n][i][c] = sum_j w[j][c]*exp2(q_j.k_i).
// grid (32, 18) x 256.  Wave owns 32 i (A = K rows, stationary); streams Q cols + w 32/iter.
// Lane (hi,jl): j = jb+jl; acc[r] (f32x4 over c) covers i = i0+(r&3)+8*(r>>2)+4*hi.
// 5-step shfl_xor reduce over jl at the end; direct float4 stores from jl==0 lanes.
__global__ __launch_bounds__(256, 2) void k_cB(float* __restrict__ ws)
{
  const int tid = threadIdx.x;
  const int w = tid >> 6, l = tid & 63;
  const int hi = l >> 5, jl = l & 31;
  const int n = blockIdx.y;
  const int i0 = blockIdx.x * 128 + w * 32;
  const short4v* qsrc = reinterpret_cast<const short4v*>(ws + OFF_QCB) + (size_t)n*NPIX;
  const short4v* ksrc = reinterpret_cast<const short4v*>(ws + OFF_KCB) + (size_t)n*NPIX;
  const f32x4* wsrc = reinterpret_cast<const f32x4*>(ws + OFF_VC) + (size_t)n*NPIX;
  const short8v ka = fragz(hi, ksrc[i0 + jl]);   // stationary A-frag (row i)
  f32x4 acc[16];
#pragma unroll
  for (int r = 0; r < 16; ++r) acc[r] = (f32x4){0.f,0.f,0.f,0.f};
  short4v qv = qsrc[jl];
  f32x4 wv = wsrc[jl];
  const f32x16 z16 = {0.f,0.f,0.f,0.f,0.f,0.f,0.f,0.f,0.f,0.f,0.f,0.f,0.f,0.f,0.f,0.f};
#pragma unroll 2
  for (int jb = 0; jb < NPIX; jb += 32) {
    short8v qb = fragz(hi, qv);                  // B-frag col j = jb+jl
    f32x4 wj = wv;
    if (jb < NPIX - 32) { qv = qsrc[jb + 32 + jl]; wv = wsrc[jb + 32 + jl]; }
    f32x16 s = MFMA32(ka, qb, z16);
#pragma unroll
    for (int r = 0; r < 16; ++r) {
      const float e = fexp2(s[r]);
      acc[r] += wj * e;
    }
  }
  // reduce over jl (lane bits 0..4); hi stays (distinct i rows)
#pragma unroll
  for (int m = 1; m < 32; m <<= 1) {
#pragma unroll
    for (int r = 0; r < 16; ++r) {
#pragma unroll
      for (int c = 0; c < 4; ++c)
        acc[r][c] += __shfl_xor(acc[r][c], m, 64);
    }
  }
  if (jl == 0) {
    f32x4* oc = reinterpret_cast<f32x4*>(ws + OFF_OUTC) + (size_t)n*NPIX;
#pragma unroll
    for (int r = 0; r < 16; ++r) {
      const int i = i0 + (r & 3) + 8*(r >> 2) + 4*hi;
      oc[i] = acc[r];
    }
  }
}

// global pass B (MFMA): OUT[c][i] += sum_j WB[c][j]*exp2(S[j][i]).  grid (64, 8) x 256
__global__ __launch_bounds__(256, 2) void k_mB(float* __restrict__ ws)
{
  __shared__ unsigned int E_dw[4][16][36];
  const unsigned short* QB = reinterpret_cast<const unsigned short*>(ws + OFF_QB);
  const unsigned short* KB = reinterpret_cast<const unsigned short*>(ws + OFF_KB);
  const unsigned short* WB = reinterpret_cast<const unsigned short*>(ws + OFF_WB);
  const int w = threadIdx.x >> 6, l = threadIdx.x & 63;
  const int g = l >> 4, li = l & 15;
  const int iw = blockIdx.x * 64 + w * 16;
  const int jbase = blockIdx.y * 512;
  short8v kb[3];
#pragma unroll
  for (int kk = 0; kk < 3; ++kk)
    kb[kk] = *reinterpret_cast<const short8v*>(KB + (iw + li)*KPAD + kk*32 + 8*g);
  f32x4 accW[5];
#pragma unroll
  for (int m = 0; m < 5; ++m) accW[m] = (f32x4){0.f, 0.f, 0.f, 0.f};
  unsigned int (*Em)[36] = E_dw[w];
  for (int t = 0; t < 16; ++t) {
    const int jb = jbase + t*32;
#pragma unroll
    for (int m = 0; m < 2; ++m) {
      f32x4 acc = {0.f, 0.f, 0.f, 0.f};
#pragma unroll
      for (int kk = 0; kk < 3; ++kk) {
        short8v qa = *reinterpret_cast<const short8v*>(QB + (jb + m*16 + li)*KPAD + kk*32 + 8*g);
        acc = MFMA(qa, kb[kk], acc);
      }
      Em[li][m*8 + 2*g    ] = bf16pair(fexp2(acc[0]), fexp2(acc[1]));
      Em[li][m*8 + 2*g + 1] = bf16pair(fexp2(acc[2]), fexp2(acc[3]));
    }
    short8v eb = *reinterpret_cast<const short8v*>(&Em[li][4*g]);
#pragma unroll
    for (int m = 0; m < 5; ++m) {
      short8v wa = *reinterpret_cast<const short8v*>(WB + (m*16 + li)*NPIX + jb + 8*g);
      accW[m] = MFMA(wa, eb, accW[m]);
    }
  }
  float* OG = ws + OFF_OUTG;
#pragma unroll
  for (int m = 0; m < 5; ++m) {
#pragma unroll
    for (int r = 0; r < 4; ++r) {
      const int c = m*16 + 4*g + r;
      if (c < NCH) atomicAdd(&OG[c*NPIX + iw + li], accW[m][r]);
    }
  }
}

// pooled[n][p] = sum_r x[4n+r][p] * (outC[n][p][r] + outG[4n+r][p]).  grid (288) x 256
__global__ void k_final(const float* __restrict__ x, const float* __restrict__ ws,
                        float* __restrict__ out)
{
  const int t = blockIdx.x * blockDim.x + threadIdx.x;
  const int n = t >> 12, p = t & 4095;
  const f32x4 oc4 = reinterpret_cast<const f32x4*>(ws + OFF_OUTC)[t];
  const float* og = ws + OFF_OUTG + (size_t)n*4*NPIX;
  float s = 0.f;
#pragma unroll
  for (int r = 0; r < 4; ++r) {
    s += x[(4*n+r)*NPIX + p] * (oc4[r] + og[r*NPIX + p]);
  }
  out[t] = s;
}

extern "C" void kernel_launch(void* const* d_in, const int* in_sizes, int n_in,
                              void* d_out, int out_size, void* d_ws, size_t ws_size,
                              hipStream_t stream)
{
  const float* x   = (const float*)d_in[0];
  const float* Wq  = (const float*)d_in[1];
  const float* bq  = (const float*)d_in[2];
  const float* Wk  = (const float*)d_in[3];
  const float* bk  = (const float*)d_in[4];
  const float* Wv  = (const float*)d_in[5];
  const float* bv  = (const float*)d_in[6];
  const float* WqG = (const float*)d_in[7];
  const float* bqG = (const float*)d_in[8];
  const float* WkG = (const float*)d_in[9];
  const float* bkG = (const float*)d_in[10];
  const float* WvG = (const float*)d_in[11];
  const float* bvG = (const float*)d_in[12];
  float* ws  = (float*)d_ws;
  float* out = (float*)d_out;

  if (ws_size < (size_t)WS_FLOATS * sizeof(float)) return; // need ~8.4 MB scratch

  // zero only the atomic accumulators: DG + OUTG (contiguous)
  hipMemsetAsync(ws + OFF_DG, 0, (size_t)(4096 + NCH*NPIX) * sizeof(float), stream);

  hipLaunchKernelGGL(k_qkv, dim3(16, 24), dim3(256), 0, stream,
                     x, Wq, bq, Wk, bk, Wv, bv, WqG, bqG, WkG, bkG, WvG, bvG, ws);
  hipLaunchKernelGGL(k_cA, dim3(32, 18), dim3(256), 0, stream, ws);
  hipLaunchKernelGGL(k_mA, dim3(64, 8), dim3(256), 0, stream, ws);
  hipLaunchKernelGGL(k_wcompG, dim3(16), dim3(256), 0, stream, ws);
  hipLaunchKernelGGL(k_cB, dim3(32, 18), dim3(256), 0, stream, ws);
  hipLaunchKernelGGL(k_mB, dim3(64, 8), dim3(256), 0, stream, ws);
  hipLaunchKernelGGL(k_final, dim3(288), dim3(256), 0, stream, x, ws, out);
}

// Round 9
// 177.761 us; speedup vs baseline: 1.1397x; 1.1397x over previous
//
#include <hip/hip_runtime.h>

#define NPIX 4096
#define NCH 72
#define NCHUNK 18
#define KPAD 96

static constexpr float SCALE_LOG2E = 0.022542110013890054f; // (1/64)*log2(e)

// ws layout (float offsets)
#define OFF_VC 0          // [18][4096][4] f32 chunk v; becomes v/D in-place after k_wcomp
#define OFF_VG 294912     // [72][4096] f32 global v (c-major)
#define OFF_DC 589824     // [18][4096] f32 (atomics; memset)
#define OFF_DG 663552     // [4096] f32 (atomics; memset)
#define OFF_OUTG 667648   // [72][4096] f32 (atomics; memset; DC..OUTG contiguous)
#define OFF_OUTC 962560   // [2][18][4096][4] f32 partials (direct-stored by k_cB)
#define OFF_QB 1552384    // bf16 [4096][96] global q (scaled, zero-padded 72..95)
#define OFF_KB 1748992    // bf16 [4096][96] global k (zero-padded)
#define OFF_WB 1945600    // bf16 [80][4096] global v/D (rows 72..79 zero)
#define OFF_QCB 2109440   // bf16 [18][4096][4] chunk q (scaled), 8B/pixel
#define OFF_KCB 2256896   // bf16 [18][4096][4] chunk k, 8B/pixel
#define WS_FLOATS 2404352

typedef __attribute__((ext_vector_type(8))) short short8v;
typedef __attribute__((ext_vector_type(4))) short short4v;
typedef __attribute__((ext_vector_type(4))) float f32x4;
typedef __attribute__((ext_vector_type(16))) float f32x16;

__device__ __forceinline__ float fexp2(float x) {
#if __has_builtin(__builtin_amdgcn_exp2f)
  return __builtin_amdgcn_exp2f(x);
#else
  return exp2f(x);
#endif
}

__device__ __forceinline__ unsigned short bf16r(float f) {
  unsigned int u = __float_as_uint(f);
  u = (u + 0x7FFFu + ((u >> 16) & 1u)) >> 16;
  return (unsigned short)u;
}
__device__ __forceinline__ unsigned int bf16pair(float lo, float hi) {
  return (unsigned int)bf16r(lo) | ((unsigned int)bf16r(hi) << 16);
}

__device__ __forceinline__ f32x4 MFMA(short8v a, short8v b, f32x4 c) {
  return __builtin_amdgcn_mfma_f32_16x16x32_bf16(a, b, c, 0, 0, 0);
}
__device__ __forceinline__ f32x16 MFMA32(short8v a, short8v b, f32x16 c) {
  return __builtin_amdgcn_mfma_f32_32x32x16_bf16(a, b, c, 0, 0, 0);
}

// Build a 32x32x16 A/B fragment from 4 real bf16 (K=4): lanes hi=1 (k=8..15) and
// elems 4..7 zeroed -> K=16 acts as K=4.
__device__ __forceinline__ short8v fragz(int hi, short4v v) {
  union { int2 i2; short4v s4; } u; u.s4 = v;
  union { int4 i4; short8v s8; } r;
  r.i4.x = hi ? 0 : u.i2.x;
  r.i4.y = hi ? 0 : u.i2.y;
  r.i4.z = 0; r.i4.w = 0;
  return r.s8;
}

__device__ __forceinline__ float dot4(float4 a, float4 b) {
  return a.x*b.x + a.y*b.y + a.z*b.z + a.w*b.w;
}

__device__ __forceinline__ float4 mix4(const float* __restrict__ W, const float* __restrict__ b,
                                       float x0, float x1, float x2, float x3, float sc)
{
  float4 r;
  r.x = (b[0] + W[0]*x0  + W[1]*x1  + W[2]*x2  + W[3]*x3)  * sc;
  r.y = (b[1] + W[4]*x0  + W[5]*x1  + W[6]*x2  + W[7]*x3)  * sc;
  r.z = (b[2] + W[8]*x0  + W[9]*x1  + W[10]*x2 + W[11]*x3) * sc;
  r.w = (b[3] + W[12]*x0 + W[13]*x1 + W[14]*x2 + W[15]*x3) * sc;
  return r;
}

// grid (16, 24) x 256. seg 0..5: chunk qkv (3 chunks each). seg 6..23: global (mat m, group of 12)
__global__ __launch_bounds__(256, 3) void k_qkv(const float* __restrict__ x,
    const float* __restrict__ Wq, const float* __restrict__ bq,
    const float* __restrict__ Wk, const float* __restrict__ bk,
    const float* __restrict__ Wv, const float* __restrict__ bv,
    const float* __restrict__ WqG, const float* __restrict__ bqG,
    const float* __restrict__ WkG, const float* __restrict__ bkG,
    const float* __restrict__ WvG, const float* __restrict__ bvG,
    float* __restrict__ ws)
{
  const int p = blockIdx.x * blockDim.x + threadIdx.x;
  const int seg = blockIdx.y;
  if (seg < 6) {
    short4v* qcb = reinterpret_cast<short4v*>(ws + OFF_QCB);
    short4v* kcb = reinterpret_cast<short4v*>(ws + OFF_KCB);
    float4* vd = reinterpret_cast<float4*>(ws + OFF_VC);
    const int n0 = seg * 3;
#pragma unroll
    for (int dn = 0; dn < 3; ++dn) {
      const int n = n0 + dn;
      const float x0 = x[(4*n+0)*NPIX + p];
      const float x1 = x[(4*n+1)*NPIX + p];
      const float x2 = x[(4*n+2)*NPIX + p];
      const float x3 = x[(4*n+3)*NPIX + p];
      float4 q = mix4(Wq + n*16, bq + n*4, x0, x1, x2, x3, SCALE_LOG2E);
      float4 k = mix4(Wk + n*16, bk + n*4, x0, x1, x2, x3, 1.0f);
      float4 v = mix4(Wv + n*16, bv + n*4, x0, x1, x2, x3, 1.0f);
      short4v qs = { (short)bf16r(q.x), (short)bf16r(q.y), (short)bf16r(q.z), (short)bf16r(q.w) };
      short4v ks = { (short)bf16r(k.x), (short)bf16r(k.y), (short)bf16r(k.z), (short)bf16r(k.w) };
      qcb[(size_t)n*NPIX + p] = qs;
      kcb[(size_t)n*NPIX + p] = ks;
      vd[n*NPIX + p] = v;
    }
  } else {
    const int m = (seg - 6) / 6;
    const int g6 = (seg - 6) % 6;
    const float* W = (m == 0) ? WqG : (m == 1) ? WkG : WvG;
    const float* b = (m == 0) ? bqG : (m == 1) ? bkG : bvG;
    float4 xv[18];
#pragma unroll
    for (int c = 0; c < 18; ++c) {
      float4 t;
      t.x = x[(4*c+0)*NPIX + p];
      t.y = x[(4*c+1)*NPIX + p];
      t.z = x[(4*c+2)*NPIX + p];
      t.w = x[(4*c+3)*NPIX + p];
      xv[c] = t;
    }
    const int ob = g6 * 12;
    if (m == 2) {
      float* dst = ws + OFF_VG; // [72][4096]
      for (int o = ob; o < ob + 12; ++o) {
        float acc = b[o];
        const float4* wrow = reinterpret_cast<const float4*>(W + o*NCH);
#pragma unroll
        for (int c = 0; c < 18; ++c) acc += dot4(wrow[c], xv[c]);
        dst[o*NPIX + p] = acc;
      }
    } else {
      unsigned short* dst = reinterpret_cast<unsigned short*>(ws + ((m == 0) ? OFF_QB : OFF_KB));
      const float sc = (m == 0) ? SCALE_LOG2E : 1.0f;
      for (int o = ob; o < ob + 12; ++o) {
        float acc = b[o];
        const float4* wrow = reinterpret_cast<const float4*>(W + o*NCH);
#pragma unroll
        for (int c = 0; c < 18; ++c) acc += dot4(wrow[c], xv[c]);
        dst[p*KPAD + o] = bf16r(acc * sc);
      }
      if (g6 == 5) {
#pragma unroll
        for (int o = NCH; o < KPAD; ++o) dst[p*KPAD + o] = 0;
      }
    }
  }
}

// chunk pass A (MFMA 32x32x16): DC[n][j] += sum_{i in strip} exp2(q_j.k_i).
// grid (32, 18, 4) x 256.  Wave owns 32 j (stationary Q B-frag); streams a 1024-i strip.
__global__ __launch_bounds__(256, 4) void k_cA(float* __restrict__ ws)
{
  const int tid = threadIdx.x;
  const int w = tid >> 6, l = tid & 63;
  const int hi = l >> 5, jl = l & 31;
  const int n = blockIdx.y;
  const int j0 = blockIdx.x * 128 + w * 32;
  const int ibase = blockIdx.z * 1024;
  const short4v* qsrc = reinterpret_cast<const short4v*>(ws + OFF_QCB) + (size_t)n*NPIX;
  const short4v* ksrc = reinterpret_cast<const short4v*>(ws + OFF_KCB) + (size_t)n*NPIX;
  const short8v qb = fragz(hi, qsrc[j0 + jl]);   // stationary B-frag (col j)
  float d[16];
#pragma unroll
  for (int r = 0; r < 16; ++r) d[r] = 0.f;
  short4v kv = ksrc[ibase + jl];
  const f32x16 z16 = {0.f,0.f,0.f,0.f,0.f,0.f,0.f,0.f,0.f,0.f,0.f,0.f,0.f,0.f,0.f,0.f};
#pragma unroll 2
  for (int ib = ibase; ib < ibase + 1024; ib += 32) {
    short8v ka = fragz(hi, kv);                  // A-frag rows i = ib+jl
    if (ib < ibase + 1024 - 32) kv = ksrc[ib + 32 + jl];
    f32x16 s = MFMA32(ka, qb, z16);
#pragma unroll
    for (int r = 0; r < 16; ++r) d[r] += fexp2(s[r]);
  }
  float dj = 0.f;
#pragma unroll
  for (int r = 0; r < 16; ++r) dj += d[r];
  dj += __shfl_xor(dj, 32, 64);                  // combine the two i-row halves
  if (hi == 0) atomicAdd(&ws[OFF_DC + n*NPIX + j0 + jl], dj);
}

// global pass A (MFMA): D[j] = sum_i exp2(S[j][i]).  grid (64, 8) x 256
__global__ __launch_bounds__(256, 2) void k_mA(float* __restrict__ ws)
{
  const unsigned short* QB = reinterpret_cast<const unsigned short*>(ws + OFF_QB);
  const unsigned short* KB = reinterpret_cast<const unsigned short*>(ws + OFF_KB);
  const int w = threadIdx.x >> 6, l = threadIdx.x & 63;
  const int g = l >> 4, li = l & 15;
  const int j0 = blockIdx.x * 64 + w * 16;
  const int i0 = blockIdx.y * 512;
  short8v qa[3];
#pragma unroll
  for (int kk = 0; kk < 3; ++kk)
    qa[kk] = *reinterpret_cast<const short8v*>(QB + (j0 + li)*KPAD + kk*32 + 8*g);
  float ds0 = 0.f, ds1 = 0.f, ds2 = 0.f, ds3 = 0.f;
  for (int t = 0; t < 32; ++t) {
    const int i = i0 + t*16;
    f32x4 acc = {0.f, 0.f, 0.f, 0.f};
#pragma unroll
    for (int kk = 0; kk < 3; ++kk) {
      short8v kb = *reinterpret_cast<const short8v*>(KB + (i + li)*KPAD + kk*32 + 8*g);
      acc = MFMA(qa[kk], kb, acc);
    }
    ds0 += fexp2(acc[0]);
    ds1 += fexp2(acc[1]);
    ds2 += fexp2(acc[2]);
    ds3 += fexp2(acc[3]);
  }
#pragma unroll
  for (int m = 1; m < 16; m <<= 1) {
    ds0 += __shfl_xor(ds0, m, 64);
    ds1 += __shfl_xor(ds1, m, 64);
    ds2 += __shfl_xor(ds2, m, 64);
    ds3 += __shfl_xor(ds3, m, 64);
  }
  if (li == 0) {
    float* D = ws + OFF_DG;
    atomicAdd(&D[j0 + 4*g + 0], ds0);
    atomicAdd(&D[j0 + 4*g + 1], ds1);
    atomicAdd(&D[j0 + 4*g + 2], ds2);
    atomicAdd(&D[j0 + 4*g + 3], ds3);
  }
}

// w = v / D.  chunk: in-place VC /= D.  global: WB = bf16(VG/D).  grid (304) x 256
__global__ void k_wcomp(float* __restrict__ ws)
{
  const int t = blockIdx.x * blockDim.x + threadIdx.x;
  if (blockIdx.x < 288) {
    const int n = t >> 12, j = t & 4095;
    const float inv = 1.0f / ws[OFF_DC + n*NPIX + j];
    float4* vc = reinterpret_cast<float4*>(ws + OFF_VC) + ((size_t)n*NPIX + j);
    float4 v = *vc;
    v.x *= inv; v.y *= inv; v.z *= inv; v.w *= inv;
    *vc = v;
  } else {
    const int j = t - NCHUNK*NPIX; // 0..4095
    const float inv = 1.0f / ws[OFF_DG + j];
    unsigned short* WB = reinterpret_cast<unsigned short*>(ws + OFF_WB);
    const float* VG = ws + OFF_VG;
#pragma unroll
    for (int c = 0; c < NCH; ++c)
      WB[c*NPIX + j] = bf16r(VG[c*NPIX + j] * inv);
#pragma unroll
    for (int c = NCH; c < 80; ++c) WB[c*NPIX + j] = 0;
  }
}

// chunk pass B (MFMA 32x32x16): OUTC[z][n][i][c] = sum_{j in strip} w[j][c]*exp2(q_j.k_i).
// grid (32, 18, 2) x 256.  Wave owns 32 i (stationary K A-frag); streams a 2048-j strip.
// Lane (hi,jl): j = jb+jl; acc[r] (f32x4 over c) covers i = i0+(r&3)+8*(r>>2)+4*hi.
__global__ __launch_bounds__(256, 2) void k_cB(float* __restrict__ ws)
{
  const int tid = threadIdx.x;
  const int w = tid >> 6, l = tid & 63;
  const int hi = l >> 5, jl = l & 31;
  const int n = blockIdx.y;
  const int i0 = blockIdx.x * 128 + w * 32;
  const int jbase = blockIdx.z * 2048;
  const short4v* qsrc = reinterpret_cast<const short4v*>(ws + OFF_QCB) + (size_t)n*NPIX;
  const short4v* ksrc = reinterpret_cast<const short4v*>(ws + OFF_KCB) + (size_t)n*NPIX;
  const f32x4* wsrc = reinterpret_cast<const f32x4*>(ws + OFF_VC) + (size_t)n*NPIX;
  const short8v ka = fragz(hi, ksrc[i0 + jl]);   // stationary A-frag (row i)
  f32x4 acc[16];
#pragma unroll
  for (int r = 0; r < 16; ++r) acc[r] = (f32x4){0.f,0.f,0.f,0.f};
  short4v qv = qsrc[jbase + jl];
  f32x4 wv = wsrc[jbase + jl];
  const f32x16 z16 = {0.f,0.f,0.f,0.f,0.f,0.f,0.f,0.f,0.f,0.f,0.f,0.f,0.f,0.f,0.f,0.f};
#pragma unroll 2
  for (int jb = jbase; jb < jbase + 2048; jb += 32) {
    short8v qb = fragz(hi, qv);                  // B-frag col j = jb+jl
    f32x4 wj = wv;
    if (jb < jbase + 2048 - 32) { qv = qsrc[jb + 32 + jl]; wv = wsrc[jb + 32 + jl]; }
    f32x16 s = MFMA32(ka, qb, z16);
#pragma unroll
    for (int r = 0; r < 16; ++r) {
      const float e = fexp2(s[r]);
      acc[r] += wj * e;
    }
  }
  // reduce over jl (lane bits 0..4); hi stays (distinct i rows)
#pragma unroll
  for (int m = 1; m < 32; m <<= 1) {
#pragma unroll
    for (int r = 0; r < 16; ++r) {
#pragma unroll
      for (int c = 0; c < 4; ++c)
        acc[r][c] += __shfl_xor(acc[r][c], m, 64);
    }
  }
  if (jl == 0) {
    f32x4* oc = reinterpret_cast<f32x4*>(ws + OFF_OUTC)
              + ((size_t)blockIdx.z*NCHUNK + n)*NPIX;
#pragma unroll
    for (int r = 0; r < 16; ++r) {
      const int i = i0 + (r & 3) + 8*(r >> 2) + 4*hi;
      oc[i] = acc[r];
    }
  }
}

// global pass B (MFMA): OUT[c][i] += sum_j WB[c][j]*exp2(S[j][i]).  grid (64, 8) x 256
__global__ __launch_bounds__(256, 2) void k_mB(float* __restrict__ ws)
{
  __shared__ unsigned int E_dw[4][16][36];
  const unsigned short* QB = reinterpret_cast<const unsigned short*>(ws + OFF_QB);
  const unsigned short* KB = reinterpret_cast<const unsigned short*>(ws + OFF_KB);
  const unsigned short* WB = reinterpret_cast<const unsigned short*>(ws + OFF_WB);
  const int w = threadIdx.x >> 6, l = threadIdx.x & 63;
  const int g = l >> 4, li = l & 15;
  const int iw = blockIdx.x * 64 + w * 16;
  const int jbase = blockIdx.y * 512;
  short8v kb[3];
#pragma unroll
  for (int kk = 0; kk < 3; ++kk)
    kb[kk] = *reinterpret_cast<const short8v*>(KB + (iw + li)*KPAD + kk*32 + 8*g);
  f32x4 accW[5];
#pragma unroll
  for (int m = 0; m < 5; ++m) accW[m] = (f32x4){0.f, 0.f, 0.f, 0.f};
  unsigned int (*Em)[36] = E_dw[w];
  for (int t = 0; t < 16; ++t) {
    const int jb = jbase + t*32;
#pragma unroll
    for (int m = 0; m < 2; ++m) {
      f32x4 acc = {0.f, 0.f, 0.f, 0.f};
#pragma unroll
      for (int kk = 0; kk < 3; ++kk) {
        short8v qa = *reinterpret_cast<const short8v*>(QB + (jb + m*16 + li)*KPAD + kk*32 + 8*g);
        acc = MFMA(qa, kb[kk], acc);
      }
      Em[li][m*8 + 2*g    ] = bf16pair(fexp2(acc[0]), fexp2(acc[1]));
      Em[li][m*8 + 2*g + 1] = bf16pair(fexp2(acc[2]), fexp2(acc[3]));
    }
    short8v eb = *reinterpret_cast<const short8v*>(&Em[li][4*g]);
#pragma unroll
    for (int m = 0; m < 5; ++m) {
      short8v wa = *reinterpret_cast<const short8v*>(WB + (m*16 + li)*NPIX + jb + 8*g);
      accW[m] = MFMA(wa, eb, accW[m]);
    }
  }
  float* OG = ws + OFF_OUTG;
#pragma unroll
  for (int m = 0; m < 5; ++m) {
#pragma unroll
    for (int r = 0; r < 4; ++r) {
      const int c = m*16 + 4*g + r;
      if (c < NCH) atomicAdd(&OG[c*NPIX + iw + li], accW[m][r]);
    }
  }
}

// pooled[n][p] = sum_r x[4n+r][p] * (outC0+outC1 + outG).  grid (288) x 256
__global__ void k_final(const float* __restrict__ x, const float* __restrict__ ws,
                        float* __restrict__ out)
{
  const int t = blockIdx.x * blockDim.x + threadIdx.x;
  const int n = t >> 12, p = t & 4095;
  const f32x4* ocp = reinterpret_cast<const f32x4*>(ws + OFF_OUTC);
  const f32x4 oc4 = ocp[(size_t)n*NPIX + p] + ocp[((size_t)NCHUNK + n)*NPIX + p];
  const float* og = ws + OFF_OUTG + (size_t)n*4*NPIX;
  float s = 0.f;
#pragma unroll
  for (int r = 0; r < 4; ++r) {
    s += x[(4*n+r)*NPIX + p] * (oc4[r] + og[r*NPIX + p]);
  }
  out[t] = s;
}

extern "C" void kernel_launch(void* const* d_in, const int* in_sizes, int n_in,
                              void* d_out, int out_size, void* d_ws, size_t ws_size,
                              hipStream_t stream)
{
  const float* x   = (const float*)d_in[0];
  const float* Wq  = (const float*)d_in[1];
  const float* bq  = (const float*)d_in[2];
  const float* Wk  = (const float*)d_in[3];
  const float* bk  = (const float*)d_in[4];
  const float* Wv  = (const float*)d_in[5];
  const float* bv  = (const float*)d_in[6];
  const float* WqG = (const float*)d_in[7];
  const float* bqG = (const float*)d_in[8];
  const float* WkG = (const float*)d_in[9];
  const float* bkG = (const float*)d_in[10];
  const float* WvG = (const float*)d_in[11];
  const float* bvG = (const float*)d_in[12];
  float* ws  = (float*)d_ws;
  float* out = (float*)d_out;

  if (ws_size < (size_t)WS_FLOATS * sizeof(float)) return; // need ~9.6 MB scratch

  // zero the atomic accumulators: DC + DG + OUTG (contiguous)
  hipMemsetAsync(ws + OFF_DC, 0, (size_t)(OFF_OUTC - OFF_DC) * sizeof(float), stream);

  hipLaunchKernelGGL(k_qkv, dim3(16, 24), dim3(256), 0, stream,
                     x, Wq, bq, Wk, bk, Wv, bv, WqG, bqG, WkG, bkG, WvG, bvG, ws);
  hipLaunchKernelGGL(k_cA, dim3(32, 18, 4), dim3(256), 0, stream, ws);
  hipLaunchKernelGGL(k_mA, dim3(64, 8), dim3(256), 0, stream, ws);
  hipLaunchKernelGGL(k_wcomp, dim3(304), dim3(256), 0, stream, ws);
  hipLaunchKernelGGL(k_cB, dim3(32, 18, 2), dim3(256), 0, stream, ws);
  hipLaunchKernelGGL(k_mB, dim3(64, 8), dim3(256), 0, stream, ws);
  hipLaunchKernelGGL(k_final, dim3(288), dim3(256), 0, stream, x, ws, out);
}

// Round 10
// 104.484 us; speedup vs baseline: 1.9390x; 1.7013x over previous
//
#include <hip/hip_runtime.h>

#define NPIX 4096
#define NCH 72
#define NCHUNK 18
#define KPAD 96

static constexpr float SCALE_LOG2E = 0.022542110013890054f; // (1/64)*log2(e)
static constexpr float SCALE_N = 0.015625f;                 // 1/64

// ws layout (float offsets)
#define OFF_QC 0          // [18][4096][4] f32 chunk q, scaled 1/64
#define OFF_KC 294912     // [18][4096][4] f32 chunk k
#define OFF_VC 589824     // [18][4096][4] f32 chunk v
#define OFF_VG 884736     // [72][4096] f32 global v (c-major)
#define OFF_DG 1179648    // [4096] f32 (atomics; memset)
#define OFF_OUTG 1183744  // [72][4096] f32 (atomics; memset; contiguous with DG)
#define OFF_QB 1478656    // bf16 [4096][96] global q (scaled, zero-padded 72..95)
#define OFF_KB 1675264    // bf16 [4096][96] global k (zero-padded)
#define OFF_WB 1871872    // bf16 [80][4096] global v/D (rows 72..79 zero)
#define OFF_SM 2035712    // [18][16] chunk K-moments: S1(4), S2'(10, diag 1/2-folded) (atomics; memset)
#define OFF_WM 2036000    // [18][64] chunk W-moments: per c<4: [M0, M1(4), M2'(10)] = 15 (atomics; memset)
#define WS_FLOATS 2037152

typedef __attribute__((ext_vector_type(8))) short short8v;
typedef __attribute__((ext_vector_type(4))) float f32x4;

__device__ __forceinline__ float fexp2(float x) {
#if __has_builtin(__builtin_amdgcn_exp2f)
  return __builtin_amdgcn_exp2f(x);
#else
  return exp2f(x);
#endif
}

__device__ __forceinline__ unsigned short bf16r(float f) {
  unsigned int u = __float_as_uint(f);
  u = (u + 0x7FFFu + ((u >> 16) & 1u)) >> 16;
  return (unsigned short)u;
}
__device__ __forceinline__ unsigned int bf16pair(float lo, float hi) {
  return (unsigned int)bf16r(lo) | ((unsigned int)bf16r(hi) << 16);
}

__device__ __forceinline__ f32x4 MFMA(short8v a, short8v b, f32x4 c) {
  return __builtin_amdgcn_mfma_f32_16x16x32_bf16(a, b, c, 0, 0, 0);
}

__device__ __forceinline__ float dot4(float4 a, float4 b) {
  return a.x*b.x + a.y*b.y + a.z*b.z + a.w*b.w;
}

__device__ __forceinline__ float4 mix4(const float* __restrict__ W, const float* __restrict__ b,
                                       float x0, float x1, float x2, float x3, float sc)
{
  float4 r;
  r.x = (b[0] + W[0]*x0  + W[1]*x1  + W[2]*x2  + W[3]*x3)  * sc;
  r.y = (b[1] + W[4]*x0  + W[5]*x1  + W[6]*x2  + W[7]*x3)  * sc;
  r.z = (b[2] + W[8]*x0  + W[9]*x1  + W[10]*x2 + W[11]*x3) * sc;
  r.w = (b[3] + W[12]*x0 + W[13]*x1 + W[14]*x2 + W[15]*x3) * sc;
  return r;
}

// grid (16, 24) x 256. seg 0..5: chunk qkv (3 chunks each, f32). seg 6..23: global (mat m, group of 12)
__global__ __launch_bounds__(256, 3) void k_qkv(const float* __restrict__ x,
    const float* __restrict__ Wq, const float* __restrict__ bq,
    const float* __restrict__ Wk, const float* __restrict__ bk,
    const float* __restrict__ Wv, const float* __restrict__ bv,
    const float* __restrict__ WqG, const float* __restrict__ bqG,
    const float* __restrict__ WkG, const float* __restrict__ bkG,
    const float* __restrict__ WvG, const float* __restrict__ bvG,
    float* __restrict__ ws)
{
  const int p = blockIdx.x * blockDim.x + threadIdx.x;
  const int seg = blockIdx.y;
  if (seg < 6) {
    float4* qd = reinterpret_cast<float4*>(ws + OFF_QC);
    float4* kd = reinterpret_cast<float4*>(ws + OFF_KC);
    float4* vd = reinterpret_cast<float4*>(ws + OFF_VC);
    const int n0 = seg * 3;
#pragma unroll
    for (int dn = 0; dn < 3; ++dn) {
      const int n = n0 + dn;
      const float x0 = x[(4*n+0)*NPIX + p];
      const float x1 = x[(4*n+1)*NPIX + p];
      const float x2 = x[(4*n+2)*NPIX + p];
      const float x3 = x[(4*n+3)*NPIX + p];
      float4 q = mix4(Wq + n*16, bq + n*4, x0, x1, x2, x3, SCALE_N);
      float4 k = mix4(Wk + n*16, bk + n*4, x0, x1, x2, x3, 1.0f);
      float4 v = mix4(Wv + n*16, bv + n*4, x0, x1, x2, x3, 1.0f);
      qd[(size_t)n*NPIX + p] = q;
      kd[(size_t)n*NPIX + p] = k;
      vd[(size_t)n*NPIX + p] = v;
    }
  } else {
    const int m = (seg - 6) / 6;
    const int g6 = (seg - 6) % 6;
    const float* W = (m == 0) ? WqG : (m == 1) ? WkG : WvG;
    const float* b = (m == 0) ? bqG : (m == 1) ? bkG : bvG;
    float4 xv[18];
#pragma unroll
    for (int c = 0; c < 18; ++c) {
      float4 t;
      t.x = x[(4*c+0)*NPIX + p];
      t.y = x[(4*c+1)*NPIX + p];
      t.z = x[(4*c+2)*NPIX + p];
      t.w = x[(4*c+3)*NPIX + p];
      xv[c] = t;
    }
    const int ob = g6 * 12;
    if (m == 2) {
      float* dst = ws + OFF_VG; // [72][4096]
      for (int o = ob; o < ob + 12; ++o) {
        float acc = b[o];
        const float4* wrow = reinterpret_cast<const float4*>(W + o*NCH);
#pragma unroll
        for (int c = 0; c < 18; ++c) acc += dot4(wrow[c], xv[c]);
        dst[o*NPIX + p] = acc;
      }
    } else {
      unsigned short* dst = reinterpret_cast<unsigned short*>(ws + ((m == 0) ? OFF_QB : OFF_KB));
      const float sc = (m == 0) ? SCALE_LOG2E : 1.0f;
      for (int o = ob; o < ob + 12; ++o) {
        float acc = b[o];
        const float4* wrow = reinterpret_cast<const float4*>(W + o*NCH);
#pragma unroll
        for (int c = 0; c < 18; ++c) acc += dot4(wrow[c], xv[c]);
        dst[p*KPAD + o] = bf16r(acc * sc);
      }
      if (g6 == 5) {
#pragma unroll
        for (int o = NCH; o < KPAD; ++o) dst[p*KPAD + o] = 0;
      }
    }
  }
}

// chunk K-moments: SM[n] = [S1(4), S2'(10, diag half)] summed over all i.  grid (4, 18) x 256
__global__ __launch_bounds__(256, 4) void k_kmom(float* __restrict__ ws)
{
  const int n = blockIdx.y;
  const int tid = threadIdx.x;
  const float4* kc = reinterpret_cast<const float4*>(ws + OFF_KC) + (size_t)n*NPIX + blockIdx.x*1024;
  float f[14];
#pragma unroll
  for (int i = 0; i < 14; ++i) f[i] = 0.f;
#pragma unroll
  for (int s = 0; s < 4; ++s) {
    float4 k = kc[s*256 + tid];
    f[0] += k.x; f[1] += k.y; f[2] += k.z; f[3] += k.w;
    f[4] += 0.5f*k.x*k.x; f[5] += k.x*k.y; f[6]  += k.x*k.z; f[7]  += k.x*k.w;
    f[8] += 0.5f*k.y*k.y; f[9] += k.y*k.z; f[10] += k.y*k.w;
    f[11] += 0.5f*k.z*k.z; f[12] += k.z*k.w; f[13] += 0.5f*k.w*k.w;
  }
#pragma unroll
  for (int m = 1; m < 64; m <<= 1) {
#pragma unroll
    for (int i = 0; i < 14; ++i) f[i] += __shfl_xor(f[i], m, 64);
  }
  if ((tid & 63) == 0) {
    float* SM = ws + OFF_SM + n*16;
#pragma unroll
    for (int i = 0; i < 14; ++i) atomicAdd(&SM[i], f[i]);
  }
}

// chunk W-moments (fused D): per pixel j compute D_j via Taylor-2, w = v/D, accumulate
// WM[n][c*15 + {M0, M1(4), M2'(10, diag half)}] = sum_j w_jc * {1, q, q⊗q}.  grid (4, 18) x 256
__global__ __launch_bounds__(256, 4) void k_cmom(float* __restrict__ ws)
{
  const int n = blockIdx.y;
  const int tid = threadIdx.x;
  const size_t base = (size_t)n*NPIX + blockIdx.x*1024;
  const float4* qc = reinterpret_cast<const float4*>(ws + OFF_QC) + base;
  const float4* vc = reinterpret_cast<const float4*>(ws + OFF_VC) + base;
  const float* SM = ws + OFF_SM + n*16;
  const float s10 = SM[0], s11 = SM[1], s12 = SM[2], s13 = SM[3];
  float s2[10];
#pragma unroll
  for (int i = 0; i < 10; ++i) s2[i] = SM[4+i];
  float mom[60];
#pragma unroll
  for (int i = 0; i < 60; ++i) mom[i] = 0.f;
#pragma unroll
  for (int s = 0; s < 4; ++s) {
    float4 q = qc[s*256 + tid];
    float4 v = vc[s*256 + tid];
    float P[10];  // plain q-products
    P[0] = q.x*q.x; P[1] = q.x*q.y; P[2] = q.x*q.z; P[3] = q.x*q.w;
    P[4] = q.y*q.y; P[5] = q.y*q.z; P[6] = q.y*q.w;
    P[7] = q.z*q.z; P[8] = q.z*q.w; P[9] = q.w*q.w;
    // D = sum_i e^{q.k_i} ~= N + q.S1 + sum S2'[ab] * plainP(q)
    float D = 4096.0f + s10*q.x + s11*q.y + s12*q.z + s13*q.w;
#pragma unroll
    for (int i = 0; i < 10; ++i) D += s2[i]*P[i];
    const float inv = 1.0f / D;
    const float wc[4] = { v.x*inv, v.y*inv, v.z*inv, v.w*inv };
    float F[15];  // coef-folded features for M accumulation
    F[0] = 1.f; F[1] = q.x; F[2] = q.y; F[3] = q.z; F[4] = q.w;
    F[5]  = 0.5f*P[0]; F[6]  = P[1]; F[7]  = P[2]; F[8] = P[3];
    F[9]  = 0.5f*P[4]; F[10] = P[5]; F[11] = P[6];
    F[12] = 0.5f*P[7]; F[13] = P[8]; F[14] = 0.5f*P[9];
#pragma unroll
    for (int c = 0; c < 4; ++c) {
#pragma unroll
      for (int i = 0; i < 15; ++i) mom[c*15 + i] += wc[c]*F[i];
    }
  }
#pragma unroll
  for (int m = 1; m < 64; m <<= 1) {
#pragma unroll
    for (int i = 0; i < 60; ++i) mom[i] += __shfl_xor(mom[i], m, 64);
  }
  if ((tid & 63) == 0) {
    float* WM = ws + OFF_WM + n*64;
#pragma unroll
    for (int i = 0; i < 60; ++i) atomicAdd(&WM[i], mom[i]);
  }
}

// global pass A (MFMA): D[j] = sum_i exp2(S[j][i]).  grid (64, 8) x 256
__global__ __launch_bounds__(256, 2) void k_mA(float* __restrict__ ws)
{
  const unsigned short* QB = reinterpret_cast<const unsigned short*>(ws + OFF_QB);
  const unsigned short* KB = reinterpret_cast<const unsigned short*>(ws + OFF_KB);
  const int w = threadIdx.x >> 6, l = threadIdx.x & 63;
  const int g = l >> 4, li = l & 15;
  const int j0 = blockIdx.x * 64 + w * 16;
  const int i0 = blockIdx.y * 512;
  short8v qa[3];
#pragma unroll
  for (int kk = 0; kk < 3; ++kk)
    qa[kk] = *reinterpret_cast<const short8v*>(QB + (j0 + li)*KPAD + kk*32 + 8*g);
  float ds0 = 0.f, ds1 = 0.f, ds2 = 0.f, ds3 = 0.f;
  for (int t = 0; t < 32; ++t) {
    const int i = i0 + t*16;
    f32x4 acc = {0.f, 0.f, 0.f, 0.f};
#pragma unroll
    for (int kk = 0; kk < 3; ++kk) {
      short8v kb = *reinterpret_cast<const short8v*>(KB + (i + li)*KPAD + kk*32 + 8*g);
      acc = MFMA(qa[kk], kb, acc);
    }
    ds0 += fexp2(acc[0]);
    ds1 += fexp2(acc[1]);
    ds2 += fexp2(acc[2]);
    ds3 += fexp2(acc[3]);
  }
#pragma unroll
  for (int m = 1; m < 16; m <<= 1) {
    ds0 += __shfl_xor(ds0, m, 64);
    ds1 += __shfl_xor(ds1, m, 64);
    ds2 += __shfl_xor(ds2, m, 64);
    ds3 += __shfl_xor(ds3, m, 64);
  }
  if (li == 0) {
    float* D = ws + OFF_DG;
    atomicAdd(&D[j0 + 4*g + 0], ds0);
    atomicAdd(&D[j0 + 4*g + 1], ds1);
    atomicAdd(&D[j0 + 4*g + 2], ds2);
    atomicAdd(&D[j0 + 4*g + 3], ds3);
  }
}

// global w: WB = bf16(VG/D).  grid (16) x 256
__global__ void k_wcompG(float* __restrict__ ws)
{
  const int j = blockIdx.x * blockDim.x + threadIdx.x; // 0..4095
  const float inv = 1.0f / ws[OFF_DG + j];
  unsigned short* WB = reinterpret_cast<unsigned short*>(ws + OFF_WB);
  const float* VG = ws + OFF_VG;
#pragma unroll
  for (int c = 0; c < NCH; ++c)
    WB[c*NPIX + j] = bf16r(VG[c*NPIX + j] * inv);
#pragma unroll
  for (int c = NCH; c < 80; ++c) WB[c*NPIX + j] = 0;
}

// global pass B (MFMA): OUT[c][i] += sum_j WB[c][j]*exp2(S[j][i]).  grid (64, 8) x 256
__global__ __launch_bounds__(256, 2) void k_mB(float* __restrict__ ws)
{
  __shared__ unsigned int E_dw[4][16][36];
  const unsigned short* QB = reinterpret_cast<const unsigned short*>(ws + OFF_QB);
  const unsigned short* KB = reinterpret_cast<const unsigned short*>(ws + OFF_KB);
  const unsigned short* WB = reinterpret_cast<const unsigned short*>(ws + OFF_WB);
  const int w = threadIdx.x >> 6, l = threadIdx.x & 63;
  const int g = l >> 4, li = l & 15;
  const int iw = blockIdx.x * 64 + w * 16;
  const int jbase = blockIdx.y * 512;
  short8v kb[3];
#pragma unroll
  for (int kk = 0; kk < 3; ++kk)
    kb[kk] = *reinterpret_cast<const short8v*>(KB + (iw + li)*KPAD + kk*32 + 8*g);
  f32x4 accW[5];
#pragma unroll
  for (int m = 0; m < 5; ++m) accW[m] = (f32x4){0.f, 0.f, 0.f, 0.f};
  unsigned int (*Em)[36] = E_dw[w];
  for (int t = 0; t < 16; ++t) {
    const int jb = jbase + t*32;
#pragma unroll
    for (int m = 0; m < 2; ++m) {
      f32x4 acc = {0.f, 0.f, 0.f, 0.f};
#pragma unroll
      for (int kk = 0; kk < 3; ++kk) {
        short8v qa = *reinterpret_cast<const short8v*>(QB + (jb + m*16 + li)*KPAD + kk*32 + 8*g);
        acc = MFMA(qa, kb[kk], acc);
      }
      Em[li][m*8 + 2*g    ] = bf16pair(fexp2(acc[0]), fexp2(acc[1]));
      Em[li][m*8 + 2*g + 1] = bf16pair(fexp2(acc[2]), fexp2(acc[3]));
    }
    short8v eb = *reinterpret_cast<const short8v*>(&Em[li][4*g]);
#pragma unroll
    for (int m = 0; m < 5; ++m) {
      short8v wa = *reinterpret_cast<const short8v*>(WB + (m*16 + li)*NPIX + jb + 8*g);
      accW[m] = MFMA(wa, eb, accW[m]);
    }
  }
  float* OG = ws + OFF_OUTG;
#pragma unroll
  for (int m = 0; m < 5; ++m) {
#pragma unroll
    for (int r = 0; r < 4; ++r) {
      const int c = m*16 + 4*g + r;
      if (c < NCH) atomicAdd(&OG[c*NPIX + iw + li], accW[m][r]);
    }
  }
}

// final: outC evaluated from moments; pooled = sum_c x*(outC + outG).  grid (288) x 256
// n = blockIdx.x>>4 (block-uniform -> scalar moment loads)
__global__ void k_final(const float* __restrict__ x, const float* __restrict__ ws,
                        float* __restrict__ out)
{
  const int n = blockIdx.x >> 4;
  const int p = ((blockIdx.x & 15) << 8) + threadIdx.x;
  const float4 k = reinterpret_cast<const float4*>(ws + OFF_KC)[(size_t)n*NPIX + p];
  const float* M = ws + OFF_WM + n*64;
  float P[10];
  P[0] = k.x*k.x; P[1] = k.x*k.y; P[2] = k.x*k.z; P[3] = k.x*k.w;
  P[4] = k.y*k.y; P[5] = k.y*k.z; P[6] = k.y*k.w;
  P[7] = k.z*k.z; P[8] = k.z*k.w; P[9] = k.w*k.w;
  const float* og = ws + OFF_OUTG + (size_t)n*4*NPIX + p;
  float s = 0.f;
#pragma unroll
  for (int c = 0; c < 4; ++c) {
    const float* mc = M + c*15;
    float oc = mc[0] + mc[1]*k.x + mc[2]*k.y + mc[3]*k.z + mc[4]*k.w;
#pragma unroll
    for (int i = 0; i < 10; ++i) oc += mc[5+i]*P[i];
    s += x[(4*n + c)*NPIX + p] * (oc + og[c*NPIX]);
  }
  out[n*NPIX + p] = s;
}

extern "C" void kernel_launch(void* const* d_in, const int* in_sizes, int n_in,
                              void* d_out, int out_size, void* d_ws, size_t ws_size,
                              hipStream_t stream)
{
  const float* x   = (const float*)d_in[0];
  const float* Wq  = (const float*)d_in[1];
  const float* bq  = (const float*)d_in[2];
  const float* Wk  = (const float*)d_in[3];
  const float* bk  = (const float*)d_in[4];
  const float* Wv  = (const float*)d_in[5];
  const float* bv  = (const float*)d_in[6];
  const float* WqG = (const float*)d_in[7];
  const float* bqG = (const float*)d_in[8];
  const float* WkG = (const float*)d_in[9];
  const float* bkG = (const float*)d_in[10];
  const float* WvG = (const float*)d_in[11];
  const float* bvG = (const float*)d_in[12];
  float* ws  = (float*)d_ws;
  float* out = (float*)d_out;

  if (ws_size < (size_t)WS_FLOATS * sizeof(float)) return; // need ~8.2 MB scratch

  // zero atomic accumulators: DG+OUTG (contiguous), SM+WM (contiguous)
  hipMemsetAsync(ws + OFF_DG, 0, (size_t)(4096 + NCH*NPIX) * sizeof(float), stream);
  hipMemsetAsync(ws + OFF_SM, 0, (size_t)(WS_FLOATS - OFF_SM) * sizeof(float), stream);

  hipLaunchKernelGGL(k_qkv, dim3(16, 24), dim3(256), 0, stream,
                     x, Wq, bq, Wk, bk, Wv, bv, WqG, bqG, WkG, bkG, WvG, bvG, ws);
  hipLaunchKernelGGL(k_kmom, dim3(4, 18), dim3(256), 0, stream, ws);
  hipLaunchKernelGGL(k_mA, dim3(64, 8), dim3(256), 0, stream, ws);
  hipLaunchKernelGGL(k_cmom, dim3(4, 18), dim3(256), 0, stream, ws);
  hipLaunchKernelGGL(k_wcompG, dim3(16), dim3(256), 0, stream, ws);
  hipLaunchKernelGGL(k_mB, dim3(64, 8), dim3(256), 0, stream, ws);
  hipLaunchKernelGGL(k_final, dim3(288), dim3(256), 0, stream, x, ws, out);
}